// Round 4
// baseline (37.197 us; speedup 1.0000x reference)
//
#include <hip/hip_runtime.h>

#define P 1024
#define NB 11
#define NBINS 1331          // 11^3
#define BATCH 8

// force a (block-uniform) float into an SGPR
#define RFL(f) __uint_as_float(__builtin_amdgcn_readfirstlane(__float_as_uint(f)))

__global__ __launch_bounds__(256) void fpfh_zero(int* __restrict__ hist) {
    int i = blockIdx.x * 256 + threadIdx.x;
    if (i < BATCH * NBINS) hist[i] = 0;
}

// One direction's histogram bin.
//   nii=|n_own|^2, sni=|n_own|, ao=n_own.delta, ax=n_other.delta,
//   ninj=ni.nj, t3=det[d,ni,nj] (direction-invariant), dd=|d|^2, rdd=rsq(dd)
// alpha = (cv.n_other)/|cv| = t3*rsq(|cv|^2),  |cv|^2 = dd*nii - ao^2 (Lagrange)
// phi   = ao/|d|
// theta = atan2(nii*ax - ao*ninj, |n_own||cv| * ninj); binned via cot compares.
__device__ __forceinline__ int bin_of(float nii, float sni, float ao, float ax,
                                      float ninj, float t3, float dd, float rdd) {
    float cvv = fmaxf(fmaf(dd, nii, -(ao * ao)), 0.0f);
    float rs  = __builtin_amdgcn_rsqf(cvv);
    float alpha = t3 * rs;
    float scv = cvv * rs;                      // |cv|
    float phi = ao * rdd;
    float y   = fmaf(nii, ax, -(ao * ninj));   // cw . n_other
    float xx  = (sni * ninj) * scv;            // |cw| * (ni.nj)
    // cot|theta| compared to cot((2m-1)pi/11), m=1..5 (monotone decreasing)
    float tq  = xx * __builtin_amdgcn_rcpf(__builtin_fabsf(y));
    int kk = (tq <  3.4056873f) + (tq <  0.86650494f) + (tq < 0.14377830f)
           + (tq < -0.45668469f) + (tq < -1.55603037f);
    int ith = (y < 0.0f) ? 5 - kk : 5 + kk;    // in [0,10]
    int ia = min((int)fmaf(alpha, 5.5f, 5.5f), NB - 1);
    int ip = min((int)fmaf(phi,   5.5f, 5.5f), NB - 1);
    int bin = (ia * NB + ip) * NB + ith;
    if (bin < 0) bin += NBINS;                 // JAX wrap-once; caller drops OOB
    return bin;
}

// Unordered-pair kernel: every pair {i<j} computed once, both direction bins
// emitted. blockIdx.x in [0,320) encodes (pair k in [0,64), slot s in [0,5)).
// Pair k owns i-tiles {k, 127-k}; slot s picks one (tile, jt) combo such that
// every (tile T, jt >= floor(8T/256)) appears exactly once; total slots = 5.
__global__ __launch_bounds__(256) void fpfh_main(const float* __restrict__ x,
                                                 int* __restrict__ ghist) {
    __shared__ int shist[NBINS];

    const int t = threadIdx.x;
    const int b = blockIdx.y;
    const int k = blockIdx.x / 5;
    const int s = blockIdx.x % 5;
    const int nA = 4 - (k >> 5);
    int T, jt;
    if (s < nA) { T = k;        jt = (k >> 5) + s; }
    else        { T = 127 - k;  jt = ((127 - k) >> 5) + (s - nA); }

    const float* xb = x + b * (P * 6);

    for (int z = t; z < NBINS; z += 256) shist[z] = 0;

    // ---- 8 i-points of tile T into SGPRs (block-uniform) ----
    float PIX[8], PIY[8], PIZ[8], NIX[8], NIY[8], NIZ[8], NII[8], SNI[8];
    #pragma unroll
    for (int il = 0; il < 8; ++il) {
        const float* xi = xb + (T * 8 + il) * 6;
        PIX[il] = RFL(xi[0]); PIY[il] = RFL(xi[1]); PIZ[il] = RFL(xi[2]);
        NIX[il] = RFL(xi[3]); NIY[il] = RFL(xi[4]); NIZ[il] = RFL(xi[5]);
        float nii = fmaf(NIX[il], NIX[il], fmaf(NIY[il], NIY[il], NIZ[il] * NIZ[il]));
        NII[il] = RFL(nii);
        SNI[il] = RFL(__builtin_amdgcn_sqrtf(nii));
    }

    // ---- this thread's j-point ----
    const int j = jt * 256 + t;
    const float* xj = xb + j * 6;
    const float pjx = xj[0], pjy = xj[1], pjz = xj[2];
    const float njx = xj[3], njy = xj[4], njz = xj[5];
    const float njj = fmaf(njx, njx, fmaf(njy, njy, njz * njz));
    const float snj = __builtin_amdgcn_sqrtf(njj);

    __syncthreads();   // shist zeroed

    #pragma unroll
    for (int il = 0; il < 8; ++il) {
        const int i = T * 8 + il;
        if (j > i) {
            const float dx = pjx - PIX[il];
            const float dy = pjy - PIY[il];
            const float dz = pjz - PIZ[il];

            const float dd   = fmaf(dx, dx, fmaf(dy, dy, dz * dz));
            const float nid  = fmaf(NIX[il], dx, fmaf(NIY[il], dy, NIZ[il] * dz));
            const float njd  = fmaf(njx, dx, fmaf(njy, dy, njz * dz));
            const float ninj = fmaf(NIX[il], njx, fmaf(NIY[il], njy, NIZ[il] * njz));

            // triple product det[d, ni, nj] = (d x ni) . nj  (shared by both dirs)
            const float cvx = fmaf(dy, NIZ[il], -(dz * NIY[il]));
            const float cvy = fmaf(dz, NIX[il], -(dx * NIZ[il]));
            const float cvz = fmaf(dx, NIY[il], -(dy * NIX[il]));
            const float t3  = fmaf(cvx, njx, fmaf(cvy, njy, cvz * njz));

            const float rdd = __builtin_amdgcn_rsqf(dd);

            const int bin1 = bin_of(NII[il], SNI[il],  nid,  njd, ninj, t3, dd, rdd);
            const int bin2 = bin_of(njj,     snj,     -njd, -nid, ninj, t3, dd, rdd);

            if ((unsigned)bin1 < (unsigned)NBINS) atomicAdd(&shist[bin1], 1);
            if ((unsigned)bin2 < (unsigned)NBINS) atomicAdd(&shist[bin2], 1);
        }
    }
    __syncthreads();

    int* gb = ghist + b * NBINS;
    for (int z = t; z < NBINS; z += 256) {
        int c = shist[z];
        if (c) atomicAdd(&gb[z], c);
    }
}

__global__ __launch_bounds__(256) void fpfh_convert(const int* __restrict__ hist,
                                                    float* __restrict__ out) {
    int i = blockIdx.x * 256 + threadIdx.x;
    if (i < BATCH * NBINS)
        out[i] = (float)hist[i] / 1047552.0f;        // P*(P-1)
}

extern "C" void kernel_launch(void* const* d_in, const int* in_sizes, int n_in,
                              void* d_out, int out_size, void* d_ws, size_t ws_size,
                              hipStream_t stream) {
    const float* x = (const float*)d_in[0];
    float* out = (float*)d_out;
    int* hist = (int*)d_ws;          // BATCH*NBINS*4 = 42,592 B of scratch

    const int nOut = BATCH * NBINS;
    fpfh_zero<<<(nOut + 255) / 256, 256, 0, stream>>>(hist);
    dim3 grid(64 * 5, BATCH);
    fpfh_main<<<grid, 256, 0, stream>>>(x, hist);
    fpfh_convert<<<(nOut + 255) / 256, 256, 0, stream>>>(hist, out);
}

// Round 5
// 28.906 us; speedup vs baseline: 1.2868x; 1.2868x over previous
//
#include <hip/hip_runtime.h>

#define P 1024
#define NB 11
#define NBINS 1331          // 11^3
#define BATCH 8
#define TI 8                // i-rows per block
#define NBLK (P / TI)       // 128 main blocks per batch

// force a (block-uniform) float into an SGPR
#define RFL(f) __uint_as_float(__builtin_amdgcn_readfirstlane(__float_as_uint(f)))

// Directed-pair kernel, round-3 structure. Each block: i-tile of 8 points
// (SGPR-resident), all 1024 j (4 register-prefetched tiles of 256).
// Flush: if npart == NBLK, exclusive plain store to partial slot blockIdx.x;
// else atomicAdd into slot blockIdx.x % npart (pre-zeroed by host memset).
__global__ __launch_bounds__(256) void fpfh_main(const float* __restrict__ x,
                                                 int* __restrict__ part,
                                                 int npart) {
    __shared__ int shist[NBINS];

    const int t  = threadIdx.x;
    const int b  = blockIdx.y;
    const int i0 = blockIdx.x * TI;
    const float* xb = x + b * (P * 6);

    for (int z = t; z < NBINS; z += 256) shist[z] = 0;

    // ---- 8 i-points into SGPRs (block-uniform) ----
    float PIX[TI], PIY[TI], PIZ[TI], NIX[TI], NIY[TI], NIZ[TI], NII[TI], SNI[TI];
    #pragma unroll
    for (int il = 0; il < TI; ++il) {
        const float* xi = xb + (i0 + il) * 6;
        PIX[il] = RFL(xi[0]); PIY[il] = RFL(xi[1]); PIZ[il] = RFL(xi[2]);
        NIX[il] = RFL(xi[3]); NIY[il] = RFL(xi[4]); NIZ[il] = RFL(xi[5]);
        float nii = fmaf(NIX[il], NIX[il], fmaf(NIY[il], NIY[il], NIZ[il] * NIZ[il]));
        NII[il] = RFL(nii);                              // |ni|^2
        SNI[il] = RFL(__builtin_amdgcn_sqrtf(nii));      // |ni|
    }

    // ---- prefetch this thread's 4 j-points (coalesced, L1/L2-resident) ----
    float pjx[4], pjy[4], pjz[4], njx[4], njy[4], njz[4];
    #pragma unroll
    for (int jt = 0; jt < 4; ++jt) {
        const float* xj = xb + (jt * 256 + t) * 6;
        pjx[jt] = xj[0]; pjy[jt] = xj[1]; pjz[jt] = xj[2];
        njx[jt] = xj[3]; njy[jt] = xj[4]; njz[jt] = xj[5];
    }

    __syncthreads();   // shist zeroed

    #pragma unroll
    for (int jt = 0; jt < 4; ++jt) {
        const int j = jt * 256 + t;

        #pragma unroll
        for (int il = 0; il < TI; ++il) {
            // delta = pos_j - pos_i
            const float dx = pjx[jt] - PIX[il];
            const float dy = pjy[jt] - PIY[il];
            const float dz = pjz[jt] - PIZ[il];

            const float dd    = fmaf(dx, dx, fmaf(dy, dy, dz * dz));
            const float nid   = fmaf(NIX[il], dx, fmaf(NIY[il], dy, NIZ[il] * dz));
            const float nidnj = fmaf(NIX[il], njx[jt],
                                fmaf(NIY[il], njy[jt], NIZ[il] * njz[jt]));
            const float ddnj  = fmaf(dx, njx[jt], fmaf(dy, njy[jt], dz * njz[jt]));

            // cv = delta x ni ;  cv . nj
            const float cvx = fmaf(dy, NIZ[il], -(dz * NIY[il]));
            const float cvy = fmaf(dz, NIX[il], -(dx * NIZ[il]));
            const float cvz = fmaf(dx, NIY[il], -(dy * NIX[il]));
            const float cvdnj = fmaf(cvx, njx[jt],
                                fmaf(cvy, njy[jt], cvz * njz[jt]));

            // |cv|^2 = dd*|ni|^2 - (ni.d)^2   (Lagrange; cv ⟂ ni)
            float cvv = fmaxf(fmaf(dd, NII[il], -(nid * nid)), 0.0f);
            const float rs    = __builtin_amdgcn_rsqf(cvv);
            const float alpha = cvdnj * rs;
            const float scv   = cvv * rs;                 // |cv|

            const float phi = nid * __builtin_amdgcn_rsqf(dd);

            // theta = atan2(y, x): y = cw.nj = |ni|^2(d.nj) - (ni.d)(ni.nj),
            //                      x = |ni||cv| * (ni.nj)
            // binned via cot|theta| against cot((2m-1)pi/11), m=1..5
            const float y_t = fmaf(NII[il], ddnj, -(nid * nidnj));
            const float x_t = (SNI[il] * nidnj) * scv;
            const float tq  = x_t * __builtin_amdgcn_rcpf(__builtin_fabsf(y_t));
            int kk = (tq <  3.40568625f) + (tq <  0.86650494f) + (tq < 0.14377830f)
                   + (tq < -0.45668469f) + (tq < -1.55603037f);
            const int ith = (y_t < 0.0f) ? 5 - kk : 5 + kk;   // in [0,10]

            int ia = min((int)fmaf(alpha, 5.5f, 5.5f), NB - 1);
            int ip = min((int)fmaf(phi,   5.5f, 5.5f), NB - 1);

            int bin = (ia * NB + ip) * NB + ith;
            if (bin < 0) bin += NBINS;               // JAX wrap-once
            if ((j != i0 + il) && ((unsigned)bin < (unsigned)NBINS))
                atomicAdd(&shist[bin], 1);           // still-OOB dropped
        }
    }
    __syncthreads();

    if (npart == NBLK) {
        int* slot = part + (b * NBLK + blockIdx.x) * NBINS;
        for (int z = t; z < NBINS; z += 256) slot[z] = shist[z];   // exclusive
    } else {
        int* slot = part + (b * npart + (blockIdx.x % npart)) * NBINS;
        for (int z = t; z < NBINS; z += 256) {
            int c = shist[z];
            if (c) atomicAdd(&slot[z], c);
        }
    }
}

// One thread per (batch, bin): sum npart partials (int, fixed order ->
// deterministic), scale, store. Lane == bin -> coalesced loads each iter.
__global__ __launch_bounds__(256) void fpfh_reduce(const int* __restrict__ part,
                                                   float* __restrict__ out,
                                                   int npart) {
    const int idx = blockIdx.x * 256 + threadIdx.x;
    if (idx >= BATCH * NBINS) return;
    const int b   = idx / NBINS;
    const int bin = idx - b * NBINS;
    const int* p  = part + b * npart * NBINS + bin;
    int s = 0;
    #pragma unroll 8
    for (int k = 0; k < npart; ++k) s += p[k * NBINS];
    out[idx] = (float)s * (1.0f / 1047552.0f);       // / (P*(P-1))
}

extern "C" void kernel_launch(void* const* d_in, const int* in_sizes, int n_in,
                              void* d_out, int out_size, void* d_ws, size_t ws_size,
                              hipStream_t stream) {
    const float* x = (const float*)d_in[0];
    float* out = (float*)d_out;
    int* part  = (int*)d_ws;

    const size_t slot_bytes = (size_t)BATCH * NBINS * sizeof(int);   // 42,592 B
    const size_t full_need  = slot_bytes * NBLK;                     // ~5.45 MB
    int npart;
    if (ws_size >= full_need) {
        npart = NBLK;                 // exclusive slots: no zeroing, no atomics
    } else {
        npart = (int)(ws_size / slot_bytes);
        if (npart < 1)   npart = 1;   // ws_size >= 42.6 KB held in all rounds
        if (npart > NBLK) npart = NBLK;
        hipMemsetAsync(d_ws, 0, slot_bytes * npart, stream);  // graph-legal
    }

    dim3 grid(NBLK, BATCH);
    fpfh_main<<<grid, 256, 0, stream>>>(x, part, npart);

    const int nOut = BATCH * NBINS;
    fpfh_reduce<<<(nOut + 255) / 256, 256, 0, stream>>>(part, out, npart);
}